// Round 3
// baseline (644.172 us; speedup 1.0000x reference)
//
#include <hip/hip_runtime.h>
#include <hip/hip_bf16.h>
#include <math.h>

// Problem:
//   x  [1024, 2, 128, 128] f32
//   w1 [8, 2, 9, 9]   conv s2 p4 -> [1024, 8, 64, 64], relu
//   w2 [8, 8, 9, 9]   conv s2 p4 -> [1024, 8, 32, 32], relu
//   w3 [32, 8, 9, 9]  conv s2 p4 -> [1024, 32, 16, 16], relu
//   per-(b,c) max over 16x16, thr = 0.75*max, zero below -> conv3_masked
//   pool = mean 16x16 -> [1024, 32]; logits = pool @ wfc.T; y = log_softmax
// Outputs concat: y (2048) ++ conv3_masked (8388608) ++ pool (32768)
//
// Direct LDS-tiled convs. Weights rearranged [ky*9+kx][co] -> wave-uniform
// broadcast reads. Input tiles staged per-ci with zero padding baked in.
// Input LDS layout uses odd-quad row strides + in-row quad XOR swizzle
// (q ^= (q>>3)&7) so the wave's ds_read_b128 pattern is uniform
// 8-lanes-per-bank-quad (conflict-free ideal). Verified by enumeration for
// both conv1 (ty 0..3 x tx 0..15) and conv2 (oy 0..7 x tx 0..7) layouts.

#define RELU(v) fmaxf((v), 0.0f)

// quad-index swizzle within a row (quad = 16B unit)
__device__ __forceinline__ int swzq(int q) { return q ^ ((q >> 3) & 7); }

// ---------------- conv1: 2ch 128x128 -> 8ch 64x64 ----------------
// block = one image x one 16-row output tile (4 tiles/image). 256 thr.
// thread: oy = oy0 + tid/16, ox = 4*(tid%16) + {0..3}, all 8 co.
// sIn rows: 164 words = 41 quads (odd). In-row quads 0..33 -> swz max 37.
__global__ __launch_bounds__(256) void conv1_kernel(
    const float* __restrict__ x, const float* __restrict__ w1,
    float* __restrict__ out1) {
  __shared__ float sIn[39 * 164];
  __shared__ float sW[81 * 8];  // [ky*9+kx][co] for current ci
  const int tid = threadIdx.x;
  const int b = blockIdx.x >> 2;
  const int oy0 = (blockIdx.x & 3) << 4;
  const int iy0 = 2 * oy0 - 4;
  const float* xb = x + (size_t)b * (2 * 128 * 128);

  const int ty = tid >> 4;   // 0..15
  const int tx = tid & 15;   // ox group
  // ky-invariant swizzled in-row word offsets for the 4 input quads
  int roff[4];
#pragma unroll
  for (int q = 0; q < 4; q++) roff[q] = swzq(2 * tx + q) * 4;

  float acc[8][4];
#pragma unroll
  for (int co = 0; co < 8; co++)
#pragma unroll
    for (int i = 0; i < 4; i++) acc[co][i] = 0.f;

#pragma unroll 1
  for (int ci = 0; ci < 2; ci++) {
    __syncthreads();  // previous stage's reads done before overwrite
    // weights: w1[co][ci][ky][kx] -> sW[(ky*9+kx)*8 + co]
    for (int i = tid; i < 648; i += 256) {
      int co = i / 81;
      int rem = i - co * 81;
      sW[rem * 8 + co] = w1[co * 162 + ci * 81 + rem];
    }
    // input rows gy = iy0 + r; col quads seg 0..33 <-> gx = seg*4-4+{0..3}
    for (int i = tid; i < 39 * 34; i += 256) {
      int r = i / 34;
      int seg = i - r * 34;
      int gy = iy0 + r;
      float4 v = make_float4(0.f, 0.f, 0.f, 0.f);
      if (gy >= 0 && gy < 128 && seg >= 1 && seg <= 32)
        v = *reinterpret_cast<const float4*>(xb + (ci * 128 + gy) * 128 + (seg * 4 - 4));
      *reinterpret_cast<float4*>(&sIn[r * 164 + swzq(seg) * 4]) = v;
    }
    __syncthreads();
#pragma unroll 1
    for (int ky = 0; ky < 9; ky++) {
      const int rb = (2 * ty + ky) * 164;
      float xv[16];
#pragma unroll
      for (int q = 0; q < 4; q++) {
        float4 t = *reinterpret_cast<const float4*>(&sIn[rb + roff[q]]);
        xv[4 * q + 0] = t.x; xv[4 * q + 1] = t.y;
        xv[4 * q + 2] = t.z; xv[4 * q + 3] = t.w;
      }
      const float* wrow = &sW[ky * 72];
#pragma unroll
      for (int kx = 0; kx < 9; kx++) {
        float4 wa = *reinterpret_cast<const float4*>(wrow + kx * 8);
        float4 wb = *reinterpret_cast<const float4*>(wrow + kx * 8 + 4);
        float wv[8] = {wa.x, wa.y, wa.z, wa.w, wb.x, wb.y, wb.z, wb.w};
#pragma unroll
        for (int co = 0; co < 8; co++)
#pragma unroll
          for (int i = 0; i < 4; i++)
            acc[co][i] = fmaf(xv[kx + 2 * i], wv[co], acc[co][i]);
      }
    }
  }
  const int oy = oy0 + ty;
  float* ob = out1 + (size_t)b * (8 * 64 * 64);
#pragma unroll
  for (int co = 0; co < 8; co++) {
    float4 v = make_float4(RELU(acc[co][0]), RELU(acc[co][1]),
                           RELU(acc[co][2]), RELU(acc[co][3]));
    *reinterpret_cast<float4*>(ob + (co * 64 + oy) * 64 + 4 * tx) = v;
  }
}

// ---------------- conv2: 8ch 64x64 -> 8ch 32x32 ----------------
// block = one image (full 32x32 output), per-ci staged. 256 thr.
// thread: oy = tid/8, ox = 4*(tid%8) + {0..3}, all 8 co.
// sIn rows: 84 words = 21 quads (odd). In-row quads 0..17 -> swz max 19.
__global__ __launch_bounds__(256) void conv2_kernel(
    const float* __restrict__ in, const float* __restrict__ w2,
    float* __restrict__ out2) {
  __shared__ float sIn[71 * 84];
  __shared__ float sW[81 * 8];  // [ky*9+kx][co] for current ci
  const int tid = threadIdx.x;
  const int b = blockIdx.x;
  const float* ib = in + (size_t)b * (8 * 64 * 64);
  const int oy = tid >> 3;  // 0..31
  const int tx = tid & 7;   // ox group
  int roff[4];
#pragma unroll
  for (int q = 0; q < 4; q++) roff[q] = swzq(2 * tx + q) * 4;

  float acc[8][4];
#pragma unroll
  for (int co = 0; co < 8; co++)
#pragma unroll
    for (int i = 0; i < 4; i++) acc[co][i] = 0.f;

#pragma unroll 1
  for (int ci = 0; ci < 8; ci++) {
    __syncthreads();
    for (int i = tid; i < 648; i += 256) {
      int co = i / 81;
      int rem = i - co * 81;
      sW[rem * 8 + co] = w2[co * 648 + ci * 81 + rem];
    }
    for (int i = tid; i < 71 * 18; i += 256) {
      int r = i / 18;
      int seg = i - r * 18;
      int gy = r - 4;
      float4 v = make_float4(0.f, 0.f, 0.f, 0.f);
      if (gy >= 0 && gy < 64 && seg >= 1 && seg <= 16)
        v = *reinterpret_cast<const float4*>(ib + (ci * 64 + gy) * 64 + (seg * 4 - 4));
      *reinterpret_cast<float4*>(&sIn[r * 84 + swzq(seg) * 4]) = v;
    }
    __syncthreads();
#pragma unroll 1
    for (int ky = 0; ky < 9; ky++) {
      const int rb = (2 * oy + ky) * 84;
      float xv[16];
#pragma unroll
      for (int q = 0; q < 4; q++) {
        float4 t = *reinterpret_cast<const float4*>(&sIn[rb + roff[q]]);
        xv[4 * q + 0] = t.x; xv[4 * q + 1] = t.y;
        xv[4 * q + 2] = t.z; xv[4 * q + 3] = t.w;
      }
      const float* wrow = &sW[ky * 72];
#pragma unroll
      for (int kx = 0; kx < 9; kx++) {
        float4 wa = *reinterpret_cast<const float4*>(wrow + kx * 8);
        float4 wb = *reinterpret_cast<const float4*>(wrow + kx * 8 + 4);
        float wv[8] = {wa.x, wa.y, wa.z, wa.w, wb.x, wb.y, wb.z, wb.w};
#pragma unroll
        for (int co = 0; co < 8; co++)
#pragma unroll
          for (int i = 0; i < 4; i++)
            acc[co][i] = fmaf(xv[kx + 2 * i], wv[co], acc[co][i]);
      }
    }
  }
  float* ob = out2 + (size_t)b * (8 * 32 * 32);
#pragma unroll
  for (int co = 0; co < 8; co++) {
    float4 v = make_float4(RELU(acc[co][0]), RELU(acc[co][1]),
                           RELU(acc[co][2]), RELU(acc[co][3]));
    *reinterpret_cast<float4*>(ob + (co * 32 + oy) * 32 + 4 * tx) = v;
  }
}

// ---------------- conv3 + mask + pool: 8ch 32x32 -> 32ch 16x16 ----------------
// block = (image, co-chunk of 8), staged 2 ci at a time. thread = one pixel.
// Input reads are b64 at ~2-way bank aliasing (free) -> no swizzle needed.
__global__ __launch_bounds__(256) void conv3_kernel(
    const float* __restrict__ in, const float* __restrict__ w3,
    float* __restrict__ masked_out, float* __restrict__ pool) {
  __shared__ float sIn[2 * 39 * 40];  // 2 input channels, padded (3120 fl)
  __shared__ float sW[2 * 81 * 8];    // [c][ky*9+kx][co'] for this chunk
  __shared__ float sMax[8];
  const int tid = threadIdx.x;
  const int b = blockIdx.x >> 2;
  const int co0 = (blockIdx.x & 3) << 3;
  const float* ib = in + (size_t)b * (8 * 32 * 32);

  const int oy = tid >> 4;  // 0..15
  const int ox = tid & 15;  // 0..15
  float acc[8];
#pragma unroll
  for (int co = 0; co < 8; co++) acc[co] = 0.f;

#pragma unroll 1
  for (int cg = 0; cg < 4; cg++) {  // ci = 2*cg, 2*cg+1
    __syncthreads();
    // weights: w3[co0+cop][2cg+c][ky][kx] -> sW[(c*81 + rem)*8 + cop]
    for (int i = tid; i < 1296; i += 256) {
      int cop = i / 162;
      int r2 = i - cop * 162;  // c*81 + rem
      sW[r2 * 8 + cop] = w3[(co0 + cop) * 648 + cg * 162 + r2];
    }
    for (int i = tid; i < 2 * 39 * 10; i += 256) {
      int c = i / 390;
      int rem = i - c * 390;
      int r = rem / 10;
      int seg = rem - r * 10;
      int gy = r - 4;
      float4 v = make_float4(0.f, 0.f, 0.f, 0.f);
      if (gy >= 0 && gy < 32 && seg >= 1 && seg <= 8)
        v = *reinterpret_cast<const float4*>(ib + ((2 * cg + c) * 32 + gy) * 32 + (seg * 4 - 4));
      *reinterpret_cast<float4*>(&sIn[(c * 39 + r) * 40 + seg * 4]) = v;
    }
    __syncthreads();
#pragma unroll 1
    for (int c = 0; c < 2; c++) {
#pragma unroll 1
      for (int ky = 0; ky < 9; ky++) {
        const int r = 2 * oy + ky;
        const float* row = &sIn[(c * 39 + r) * 40 + 2 * ox];
        float xv[10];
#pragma unroll
        for (int q = 0; q < 5; q++) {
          float2 t = *reinterpret_cast<const float2*>(row + 2 * q);
          xv[2 * q + 0] = t.x; xv[2 * q + 1] = t.y;
        }
        const float* wrow = &sW[(c * 81 + ky * 9) * 8];
#pragma unroll
        for (int kx = 0; kx < 9; kx++) {
          float4 wa = *reinterpret_cast<const float4*>(wrow + kx * 8);
          float4 wb = *reinterpret_cast<const float4*>(wrow + kx * 8 + 4);
          float wv[8] = {wa.x, wa.y, wa.z, wa.w, wb.x, wb.y, wb.z, wb.w};
#pragma unroll
          for (int co = 0; co < 8; co++)
            acc[co] = fmaf(xv[kx], wv[co], acc[co]);
        }
      }
    }
  }
#pragma unroll
  for (int co = 0; co < 8; co++) acc[co] = RELU(acc[co]);

  // -------- per-channel max over the 256 pixels --------
  __syncthreads();       // compute reads of sIn done; reuse as scratch
  float* red = sIn;      // [8][256] = 2048 floats <= 3120
#pragma unroll
  for (int co = 0; co < 8; co++) red[co * 256 + tid] = acc[co];
  __syncthreads();
  {
    const int co = tid >> 5;  // 0..7
    const int j = tid & 31;
    float m = 0.f;  // relu output >= 0
    for (int p = j; p < 256; p += 32) m = fmaxf(m, red[co * 256 + p]);
#pragma unroll
    for (int k = 16; k >= 1; k >>= 1) m = fmaxf(m, __shfl_xor(m, k));
    if (j == 0) sMax[co] = m * 0.75f;
  }
  __syncthreads();

  // -------- threshold, write masked, accumulate mean --------
  float* mb = masked_out + ((size_t)b * 32 + co0) * 256 + tid;
#pragma unroll
  for (int co = 0; co < 8; co++) {
    float v = acc[co];
    v = (v < sMax[co]) ? 0.f : v;
    red[co * 256 + tid] = v;
    mb[co * 256] = v;
  }
  __syncthreads();
  {
    const int co = tid >> 5;
    const int j = tid & 31;
    float s = 0.f;
    for (int p = j; p < 256; p += 32) s += red[co * 256 + p];
#pragma unroll
    for (int k = 16; k >= 1; k >>= 1) s += __shfl_xor(s, k);
    if (j == 0) pool[(size_t)b * 32 + co0 + co] = s * (1.0f / 256.0f);
  }
}

// ---------------- head: pool @ wfc.T -> log_softmax ----------------
__global__ __launch_bounds__(256) void head_kernel(
    const float* __restrict__ pool, const float* __restrict__ wfc,
    float* __restrict__ y) {
  __shared__ float sw[64];
  if (threadIdx.x < 64) sw[threadIdx.x] = wfc[threadIdx.x];
  __syncthreads();
  const int b = blockIdx.x * 256 + threadIdx.x;  // 0..1023
  const float* pb = pool + (size_t)b * 32;
  float l0 = 0.f, l1 = 0.f;
#pragma unroll
  for (int q = 0; q < 8; q++) {
    float4 p = *reinterpret_cast<const float4*>(pb + 4 * q);
    l0 += p.x * sw[4 * q + 0] + p.y * sw[4 * q + 1] +
          p.z * sw[4 * q + 2] + p.w * sw[4 * q + 3];
    l1 += p.x * sw[32 + 4 * q + 0] + p.y * sw[32 + 4 * q + 1] +
          p.z * sw[32 + 4 * q + 2] + p.w * sw[32 + 4 * q + 3];
  }
  float m = fmaxf(l0, l1);
  float lz = logf(expf(l0 - m) + expf(l1 - m)) + m;
  float2 out = make_float2(l0 - lz, l1 - lz);
  *reinterpret_cast<float2*>(y + 2 * b) = out;
}

extern "C" void kernel_launch(void* const* d_in, const int* in_sizes, int n_in,
                              void* d_out, int out_size, void* d_ws, size_t ws_size,
                              hipStream_t stream) {
  const float* x   = (const float*)d_in[0];
  const float* w1  = (const float*)d_in[1];
  const float* w2  = (const float*)d_in[2];
  const float* w3  = (const float*)d_in[3];
  const float* wfc = (const float*)d_in[4];

  float* out = (float*)d_out;
  float* y      = out;                           // [1024, 2]
  float* masked = out + 2048;                    // [1024, 32, 16, 16]
  float* pool   = out + 2048 + 1024 * 32 * 256;  // [1024, 32]

  // workspace: conv1 out (128 MiB) ++ conv2 out (32 MiB) = 160 MiB
  float* c1 = (float*)d_ws;
  float* c2 = c1 + (size_t)1024 * 8 * 64 * 64;

  conv1_kernel<<<4096, 256, 0, stream>>>(x, w1, c1);
  conv2_kernel<<<1024, 256, 0, stream>>>(c1, w2, c2);
  conv3_kernel<<<4096, 256, 0, stream>>>(c2, w3, masked, pool);
  head_kernel<<<4, 256, 0, stream>>>(pool, wfc, y);
}

// Round 9
// 517.795 us; speedup vs baseline: 1.2441x; 1.2441x over previous
//
#include <hip/hip_runtime.h>
#include <hip/hip_bf16.h>
#include <math.h>

// Problem:
//   x  [1024, 2, 128, 128] f32
//   w1 [8, 2, 9, 9]   conv s2 p4 -> [1024, 8, 64, 64], relu
//   w2 [8, 8, 9, 9]   conv s2 p4 -> [1024, 8, 32, 32], relu
//   w3 [32, 8, 9, 9]  conv s2 p4 -> [1024, 32, 16, 16], relu
//   per-(b,c) max over 16x16, thr = 0.75*max, zero below -> conv3_masked
//   pool = mean 16x16 -> [1024, 32]; logits = pool @ wfc.T; y = log_softmax
// Outputs concat: y (2048) ++ conv3_masked (8388608) ++ pool (32768)
//
// R3 insight (rocprof): conv3 VALUBusy=43% == LDS-pipe-bound on 18 b128
// weight-broadcast reads per 144 VALU cyc. LDS pipe is per-CU, VALU per-SIMD
// -> need VALU_cyc > 4x LDS_cyc per wave. Fix: weights via WAVE-UNIFORM
// global loads -> s_load (SMEM pipe, SGPR operand of v_fma) -> zero LDS
// traffic for weights. Input tiles stay in LDS (swizzled, conflict-free).
// (R4-R8 benches were infra failures; resubmitting the same design.)

#define RELU(v) fmaxf((v), 0.0f)

// quad-index swizzle within a row (quad = 16B unit)
__device__ __forceinline__ int swzq(int q) { return q ^ ((q >> 3) & 7); }

// ---------------- conv1: 2ch 128x128 -> 8ch 64x64 ----------------
// block = one image x one 16-row output tile. 256 thr.
// thread: oy = oy0 + tid/16, ox = 4*(tid%16) + {0..3}, all 8 co.
// sIn rows: 164 words = 41 quads (odd). Swizzled -> conflict-free b128.
__global__ __launch_bounds__(256) void conv1_kernel(
    const float* __restrict__ x, const float* __restrict__ w1,
    float* __restrict__ out1) {
  __shared__ float sIn[39 * 164];
  const int tid = threadIdx.x;
  const int b = blockIdx.x >> 2;
  const int oy0 = (blockIdx.x & 3) << 4;
  const int iy0 = 2 * oy0 - 4;
  const float* xb = x + (size_t)b * (2 * 128 * 128);

  const int ty = tid >> 4;   // 0..15
  const int tx = tid & 15;   // ox group
  int roff[4];
#pragma unroll
  for (int q = 0; q < 4; q++) roff[q] = swzq(2 * tx + q) * 4;

  float acc[8][4];
#pragma unroll
  for (int co = 0; co < 8; co++)
#pragma unroll
    for (int i = 0; i < 4; i++) acc[co][i] = 0.f;

#pragma unroll 1
  for (int ci = 0; ci < 2; ci++) {
    __syncthreads();  // previous stage's reads done before overwrite
    for (int i = tid; i < 39 * 34; i += 256) {
      int r = i / 34;
      int seg = i - r * 34;
      int gy = iy0 + r;
      float4 v = make_float4(0.f, 0.f, 0.f, 0.f);
      if (gy >= 0 && gy < 128 && seg >= 1 && seg <= 32)
        v = *reinterpret_cast<const float4*>(xb + (ci * 128 + gy) * 128 + (seg * 4 - 4));
      *reinterpret_cast<float4*>(&sIn[r * 164 + swzq(seg) * 4]) = v;
    }
    __syncthreads();
#pragma unroll 1
    for (int ky = 0; ky < 9; ky++) {
      const int rb = (2 * ty + ky) * 164;
      float xv[16];
#pragma unroll
      for (int q = 0; q < 4; q++) {
        float4 t = *reinterpret_cast<const float4*>(&sIn[rb + roff[q]]);
        xv[4 * q + 0] = t.x; xv[4 * q + 1] = t.y;
        xv[4 * q + 2] = t.z; xv[4 * q + 3] = t.w;
      }
      // weights: wave-uniform address -> scalar loads (SMEM pipe)
#pragma unroll
      for (int co = 0; co < 8; co++) {
        const float* wr = w1 + (co * 2 + ci) * 81 + ky * 9;
        float w[9];
#pragma unroll
        for (int k = 0; k < 9; k++) w[k] = wr[k];
#pragma unroll
        for (int kx = 0; kx < 9; kx++)
#pragma unroll
          for (int i = 0; i < 4; i++)
            acc[co][i] = fmaf(xv[kx + 2 * i], w[kx], acc[co][i]);
      }
    }
  }
  const int oy = oy0 + ty;
  float* ob = out1 + (size_t)b * (8 * 64 * 64);
#pragma unroll
  for (int co = 0; co < 8; co++) {
    float4 v = make_float4(RELU(acc[co][0]), RELU(acc[co][1]),
                           RELU(acc[co][2]), RELU(acc[co][3]));
    *reinterpret_cast<float4*>(ob + (co * 64 + oy) * 64 + 4 * tx) = v;
  }
}

// ---------------- conv2: 8ch 64x64 -> 8ch 32x32 ----------------
// block = one image (full 32x32 output), per-ci staged. 256 thr.
__global__ __launch_bounds__(256) void conv2_kernel(
    const float* __restrict__ in, const float* __restrict__ w2,
    float* __restrict__ out2) {
  __shared__ float sIn[71 * 84];  // 84 words = 21 quads (odd), swizzled
  const int tid = threadIdx.x;
  const int b = blockIdx.x;
  const float* ib = in + (size_t)b * (8 * 64 * 64);
  const int oy = tid >> 3;  // 0..31
  const int tx = tid & 7;   // ox group
  int roff[4];
#pragma unroll
  for (int q = 0; q < 4; q++) roff[q] = swzq(2 * tx + q) * 4;

  float acc[8][4];
#pragma unroll
  for (int co = 0; co < 8; co++)
#pragma unroll
    for (int i = 0; i < 4; i++) acc[co][i] = 0.f;

#pragma unroll 1
  for (int ci = 0; ci < 8; ci++) {
    __syncthreads();
    for (int i = tid; i < 71 * 18; i += 256) {
      int r = i / 18;
      int seg = i - r * 18;
      int gy = r - 4;
      float4 v = make_float4(0.f, 0.f, 0.f, 0.f);
      if (gy >= 0 && gy < 64 && seg >= 1 && seg <= 16)
        v = *reinterpret_cast<const float4*>(ib + (ci * 64 + gy) * 64 + (seg * 4 - 4));
      *reinterpret_cast<float4*>(&sIn[r * 84 + swzq(seg) * 4]) = v;
    }
    __syncthreads();
#pragma unroll 1
    for (int ky = 0; ky < 9; ky++) {
      const int rb = (2 * oy + ky) * 84;
      float xv[16];
#pragma unroll
      for (int q = 0; q < 4; q++) {
        float4 t = *reinterpret_cast<const float4*>(&sIn[rb + roff[q]]);
        xv[4 * q + 0] = t.x; xv[4 * q + 1] = t.y;
        xv[4 * q + 2] = t.z; xv[4 * q + 3] = t.w;
      }
#pragma unroll
      for (int co = 0; co < 8; co++) {
        const float* wr = w2 + (co * 8 + ci) * 81 + ky * 9;
        float w[9];
#pragma unroll
        for (int k = 0; k < 9; k++) w[k] = wr[k];
#pragma unroll
        for (int kx = 0; kx < 9; kx++)
#pragma unroll
          for (int i = 0; i < 4; i++)
            acc[co][i] = fmaf(xv[kx + 2 * i], w[kx], acc[co][i]);
      }
    }
  }
  float* ob = out2 + (size_t)b * (8 * 32 * 32);
#pragma unroll
  for (int co = 0; co < 8; co++) {
    float4 v = make_float4(RELU(acc[co][0]), RELU(acc[co][1]),
                           RELU(acc[co][2]), RELU(acc[co][3]));
    *reinterpret_cast<float4*>(ob + (co * 32 + oy) * 32 + 4 * tx) = v;
  }
}

// ---------------- conv3 + mask + pool: 8ch 32x32 -> 32ch 16x16 ----------------
// block = ONE image, 256 thr. Wave w owns co-chunk w (8 channels) and the
// full 16x16 tile: lane p: oy=p>>2, ox=4*(p&3)+{0..3}, acc[8][4].
// Weights scalar-loaded (readfirstlane-forced uniform chunk). Max/pool are
// pure in-wave shfl_xor butterflies -> no LDS epilogue, no barriers.
__global__ __launch_bounds__(256) void conv3_kernel(
    const float* __restrict__ in, const float* __restrict__ w3,
    float* __restrict__ masked_out, float* __restrict__ pool) {
  __shared__ float sIn[2 * 39 * 44];  // 2 ci, 11-quad row stride
  const int tid = threadIdx.x;
  const int b = blockIdx.x;
  const int co0 = __builtin_amdgcn_readfirstlane(tid >> 6) * 8;  // wave-uniform
  const int p = tid & 63;
  const int oy = p >> 2;   // 0..15
  const int oxg = p & 3;   // ox = 4*oxg + {0..3}
  const float* ib = in + (size_t)b * (8 * 32 * 32);

  float acc[8][4];
#pragma unroll
  for (int co = 0; co < 8; co++)
#pragma unroll
    for (int i = 0; i < 4; i++) acc[co][i] = 0.f;

#pragma unroll 1
  for (int cg = 0; cg < 4; cg++) {  // ci = 2*cg, 2*cg+1
    __syncthreads();
    for (int i = tid; i < 2 * 39 * 10; i += 256) {
      int c = i / 390;
      int rem = i - c * 390;
      int r = rem / 10;
      int seg = rem - r * 10;
      int gy = r - 4;
      float4 v = make_float4(0.f, 0.f, 0.f, 0.f);
      if (gy >= 0 && gy < 32 && seg >= 1 && seg <= 8)
        v = *reinterpret_cast<const float4*>(ib + ((2 * cg + c) * 32 + gy) * 32 + (seg * 4 - 4));
      *reinterpret_cast<float4*>(&sIn[(c * 39 + r) * 44 + seg * 4]) = v;
    }
    __syncthreads();
#pragma unroll 1
    for (int c = 0; c < 2; c++) {
      const int ci = 2 * cg + c;
#pragma unroll 1
      for (int ky = 0; ky < 9; ky++) {
        const int rb = (c * 39 + 2 * oy + ky) * 44;
        float xv[16];
#pragma unroll
        for (int q = 0; q < 4; q++) {
          float4 t = *reinterpret_cast<const float4*>(&sIn[rb + (2 * oxg + q) * 4]);
          xv[4 * q + 0] = t.x; xv[4 * q + 1] = t.y;
          xv[4 * q + 2] = t.z; xv[4 * q + 3] = t.w;
        }
#pragma unroll
        for (int co = 0; co < 8; co++) {
          const float* wr = w3 + ((co0 + co) * 8 + ci) * 81 + ky * 9;
          float w[9];
#pragma unroll
          for (int k = 0; k < 9; k++) w[k] = wr[k];
#pragma unroll
          for (int kx = 0; kx < 9; kx++)
#pragma unroll
            for (int i = 0; i < 4; i++)
              acc[co][i] = fmaf(xv[kx + 2 * i], w[kx], acc[co][i]);
        }
      }
    }
  }

  // relu + in-wave per-co max (whole 16x16 lives in this wave)
  float thr[8];
#pragma unroll
  for (int co = 0; co < 8; co++) {
#pragma unroll
    for (int i = 0; i < 4; i++) acc[co][i] = RELU(acc[co][i]);
    float m = fmaxf(fmaxf(acc[co][0], acc[co][1]), fmaxf(acc[co][2], acc[co][3]));
#pragma unroll
    for (int k = 32; k >= 1; k >>= 1) m = fmaxf(m, __shfl_xor(m, k));
    thr[co] = m * 0.75f;
  }

  // threshold, masked store (coalesced float4: offset 4*p), pool sum
  float* mb = masked_out + ((size_t)b * 32 + co0) * 256 + 4 * p;
  float sum[8];
#pragma unroll
  for (int co = 0; co < 8; co++) {
    float4 v;
    v.x = (acc[co][0] < thr[co]) ? 0.f : acc[co][0];
    v.y = (acc[co][1] < thr[co]) ? 0.f : acc[co][1];
    v.z = (acc[co][2] < thr[co]) ? 0.f : acc[co][2];
    v.w = (acc[co][3] < thr[co]) ? 0.f : acc[co][3];
    *reinterpret_cast<float4*>(mb + co * 256) = v;
    float s = v.x + v.y + v.z + v.w;
#pragma unroll
    for (int k = 32; k >= 1; k >>= 1) s += __shfl_xor(s, k);
    sum[co] = s;
  }
  if (p == 0) {
#pragma unroll
    for (int co = 0; co < 8; co++)
      pool[(size_t)b * 32 + co0 + co] = sum[co] * (1.0f / 256.0f);
  }
}

// ---------------- head: pool @ wfc.T -> log_softmax ----------------
__global__ __launch_bounds__(256) void head_kernel(
    const float* __restrict__ pool, const float* __restrict__ wfc,
    float* __restrict__ y) {
  __shared__ float sw[64];
  if (threadIdx.x < 64) sw[threadIdx.x] = wfc[threadIdx.x];
  __syncthreads();
  const int b = blockIdx.x * 256 + threadIdx.x;  // 0..1023
  const float* pb = pool + (size_t)b * 32;
  float l0 = 0.f, l1 = 0.f;
#pragma unroll
  for (int q = 0; q < 8; q++) {
    float4 p = *reinterpret_cast<const float4*>(pb + 4 * q);
    l0 += p.x * sw[4 * q + 0] + p.y * sw[4 * q + 1] +
          p.z * sw[4 * q + 2] + p.w * sw[4 * q + 3];
    l1 += p.x * sw[32 + 4 * q + 0] + p.y * sw[32 + 4 * q + 1] +
          p.z * sw[32 + 4 * q + 2] + p.w * sw[32 + 4 * q + 3];
  }
  float m = fmaxf(l0, l1);
  float lz = logf(expf(l0 - m) + expf(l1 - m)) + m;
  float2 out = make_float2(l0 - lz, l1 - lz);
  *reinterpret_cast<float2*>(y + 2 * b) = out;
}

extern "C" void kernel_launch(void* const* d_in, const int* in_sizes, int n_in,
                              void* d_out, int out_size, void* d_ws, size_t ws_size,
                              hipStream_t stream) {
  const float* x   = (const float*)d_in[0];
  const float* w1  = (const float*)d_in[1];
  const float* w2  = (const float*)d_in[2];
  const float* w3  = (const float*)d_in[3];
  const float* wfc = (const float*)d_in[4];

  float* out = (float*)d_out;
  float* y      = out;                           // [1024, 2]
  float* masked = out + 2048;                    // [1024, 32, 16, 16]
  float* pool   = out + 2048 + 1024 * 32 * 256;  // [1024, 32]

  // workspace: conv1 out (128 MiB) ++ conv2 out (32 MiB)
  float* c1 = (float*)d_ws;
  float* c2 = c1 + (size_t)1024 * 8 * 64 * 64;

  conv1_kernel<<<4096, 256, 0, stream>>>(x, w1, c1);
  conv2_kernel<<<1024, 256, 0, stream>>>(c1, w2, c2);
  conv3_kernel<<<1024, 256, 0, stream>>>(c2, w3, masked, pool);
  head_kernel<<<4, 256, 0, stream>>>(pool, wfc, y);
}

// Round 13
// 515.898 us; speedup vs baseline: 1.2486x; 1.0037x over previous
//
#include <hip/hip_runtime.h>
#include <hip/hip_bf16.h>
#include <math.h>

// Problem:
//   x  [1024, 2, 128, 128] f32
//   w1 [8, 2, 9, 9]   conv s2 p4 -> [1024, 8, 64, 64], relu
//   w2 [8, 8, 9, 9]   conv s2 p4 -> [1024, 8, 32, 32], relu
//   w3 [32, 8, 9, 9]  conv s2 p4 -> [1024, 32, 16, 16], relu
//   per-(b,c) max over 16x16, thr = 0.75*max, zero below -> conv3_masked
//   pool = mean 16x16 -> [1024, 32]; logits = pool @ wfc.T; y = log_softmax
// Outputs concat: y (2048) ++ conv3_masked (8388608) ++ pool (32768)
//
// R9 measured: conv1 140us VALUBusy=70% occ=55%; weights-in-SGPR confirmed
// (SGPR=112). R10 changes: (a) async-STAGE split (issue global loads to regs
// before compute, ds_write after barrier) in all convs; (b) div-free staging
// index math; (c) conv2 split to 2 blocks/image (grid 2048 -> 8 blk/CU);
// (d) conv3 16-quad rows + parity-correct swizzle seg^((row>>1)&7) (fixes a
// 2x bank conflict: read quad terms 2oy/2oxg are all even -> key must use
// r>>1); (e) head fused into conv3.
// (R10-R12 benches were infra failures; resubmitting unchanged.)

#define RELU(v) fmaxf((v), 0.0f)

// quad-index swizzle within a row (quad = 16B unit)
__device__ __forceinline__ int swzq(int q) { return q ^ ((q >> 3) & 7); }

// ---------------- conv1: 2ch 128x128 -> 8ch 64x64 ----------------
// block = one image x one 16-row output tile. 256 thr.
// thread: oy = oy0 + tid/16, ox = 4*(tid%16) + {0..3}, all 8 co.
// sIn rows: 164 words = 41 quads (odd) + swzq -> conflict-free b128 reads.
__global__ __launch_bounds__(256) void conv1_kernel(
    const float* __restrict__ x, const float* __restrict__ w1,
    float* __restrict__ out1) {
  __shared__ float sIn[39 * 164];
  const int tid = threadIdx.x;
  const int b = blockIdx.x >> 2;
  const int oy0 = (blockIdx.x & 3) << 4;
  const int iy0 = 2 * oy0 - 4;
  const float* xb = x + (size_t)b * (2 * 128 * 128);

  const int ty = tid >> 4;   // 0..15
  const int tx = tid & 15;   // ox group
  int roff[4];
#pragma unroll
  for (int q = 0; q < 4; q++) roff[q] = swzq(2 * tx + q) * 4;

  float acc[8][4];
#pragma unroll
  for (int co = 0; co < 8; co++)
#pragma unroll
    for (int i = 0; i < 4; i++) acc[co][i] = 0.f;

  float4 pre[6];
  // issue global loads for channel ci into pre (div-free: 39 rows x 34 segs;
  // main = segs 0..31 (1248 elems), thin = segs 32,33 (78 elems))
  auto issue = [&](int ci) {
#pragma unroll
    for (int k = 0; k < 5; k++) {
      int idx = tid + 256 * k;
      int r = idx >> 5, seg = idx & 31;
      int gy = iy0 + r;
      float4 v = make_float4(0.f, 0.f, 0.f, 0.f);
      if (idx < 1248 && gy >= 0 && gy < 128 && seg >= 1)
        v = *reinterpret_cast<const float4*>(xb + (ci * 128 + gy) * 128 + (seg * 4 - 4));
      pre[k] = v;
    }
    {
      int r = tid >> 1, seg = 32 + (tid & 1);
      int gy = iy0 + r;
      float4 v = make_float4(0.f, 0.f, 0.f, 0.f);
      if (tid < 78 && gy >= 0 && gy < 128 && seg == 32)
        v = *reinterpret_cast<const float4*>(xb + (ci * 128 + gy) * 128 + (seg * 4 - 4));
      pre[5] = v;
    }
  };
  auto wrlds = [&]() {
#pragma unroll
    for (int k = 0; k < 5; k++) {
      int idx = tid + 256 * k;
      int r = idx >> 5, seg = idx & 31;
      if (idx < 1248)
        *reinterpret_cast<float4*>(&sIn[r * 164 + swzq(seg) * 4]) = pre[k];
    }
    if (tid < 78) {
      int r = tid >> 1, seg = 32 + (tid & 1);
      *reinterpret_cast<float4*>(&sIn[r * 164 + swzq(seg) * 4]) = pre[5];
    }
  };
  auto compute = [&](int ci) {
#pragma unroll 1
    for (int ky = 0; ky < 9; ky++) {
      const int rb = (2 * ty + ky) * 164;
      float xv[16];
#pragma unroll
      for (int q = 0; q < 4; q++) {
        float4 t = *reinterpret_cast<const float4*>(&sIn[rb + roff[q]]);
        xv[4 * q + 0] = t.x; xv[4 * q + 1] = t.y;
        xv[4 * q + 2] = t.z; xv[4 * q + 3] = t.w;
      }
#pragma unroll
      for (int co = 0; co < 8; co++) {
        const float* wr = w1 + (co * 2 + ci) * 81 + ky * 9;  // wave-uniform
        float w[9];
#pragma unroll
        for (int k = 0; k < 9; k++) w[k] = wr[k];
#pragma unroll
        for (int kx = 0; kx < 9; kx++)
#pragma unroll
          for (int i = 0; i < 4; i++)
            acc[co][i] = fmaf(xv[kx + 2 * i], w[kx], acc[co][i]);
      }
    }
  };

  issue(0); wrlds(); __syncthreads();
  issue(1);                 // in flight during compute(0)
  compute(0);
  __syncthreads(); wrlds(); __syncthreads();
  compute(1);

  const int oy = oy0 + ty;
  float* ob = out1 + (size_t)b * (8 * 64 * 64);
#pragma unroll
  for (int co = 0; co < 8; co++) {
    float4 v = make_float4(RELU(acc[co][0]), RELU(acc[co][1]),
                           RELU(acc[co][2]), RELU(acc[co][3]));
    *reinterpret_cast<float4*>(ob + (co * 64 + oy) * 64 + 4 * tx) = v;
  }
}

// ---------------- conv2: 8ch 64x64 -> 8ch 32x32 ----------------
// block = HALF an image (16 output rows), grid 2048 -> 8 blocks/CU. 256 thr.
// thread: oy = tid/16 (local 0..15), ox = 2*(tid%16) + {0,1}, all 8 co.
// sIn: 39 rows x 84 words (21 quads, odd) + swzq.
__global__ __launch_bounds__(256) void conv2_kernel(
    const float* __restrict__ in, const float* __restrict__ w2,
    float* __restrict__ out2) {
  __shared__ float sIn[39 * 84];
  const int tid = threadIdx.x;
  const int b = blockIdx.x >> 1;
  const int oy0 = (blockIdx.x & 1) << 4;
  const int gy0 = 2 * oy0 - 4;
  const float* ib = in + (size_t)b * (8 * 64 * 64);
  const int oy = tid >> 4;  // local 0..15
  const int tx = tid & 15;  // ox pair group
  int roff[3];
#pragma unroll
  for (int q = 0; q < 3; q++) roff[q] = swzq(tx + q) * 4;

  float acc[8][2];
#pragma unroll
  for (int co = 0; co < 8; co++) { acc[co][0] = 0.f; acc[co][1] = 0.f; }

  float4 pre[4];
  // 39 rows x 18 segs: main segs 0..15 (624), thin segs 16,17 (78)
  auto issue = [&](int ci) {
#pragma unroll
    for (int k = 0; k < 3; k++) {
      int idx = tid + 256 * k;
      int r = idx >> 4, seg = idx & 15;
      int gy = gy0 + r;
      float4 v = make_float4(0.f, 0.f, 0.f, 0.f);
      if (idx < 624 && gy >= 0 && gy < 64 && seg >= 1)
        v = *reinterpret_cast<const float4*>(ib + (ci * 64 + gy) * 64 + (seg * 4 - 4));
      pre[k] = v;
    }
    {
      int r = tid >> 1, seg = 16 + (tid & 1);
      int gy = gy0 + r;
      float4 v = make_float4(0.f, 0.f, 0.f, 0.f);
      if (tid < 78 && gy >= 0 && gy < 64 && seg == 16)
        v = *reinterpret_cast<const float4*>(ib + (ci * 64 + gy) * 64 + (seg * 4 - 4));
      pre[3] = v;
    }
  };
  auto wrlds = [&]() {
#pragma unroll
    for (int k = 0; k < 3; k++) {
      int idx = tid + 256 * k;
      int r = idx >> 4, seg = idx & 15;
      if (idx < 624)
        *reinterpret_cast<float4*>(&sIn[r * 84 + swzq(seg) * 4]) = pre[k];
    }
    if (tid < 78) {
      int r = tid >> 1, seg = 16 + (tid & 1);
      *reinterpret_cast<float4*>(&sIn[r * 84 + swzq(seg) * 4]) = pre[3];
    }
  };
  auto compute = [&](int ci) {
#pragma unroll 1
    for (int ky = 0; ky < 9; ky++) {
      const int rb = (2 * oy + ky) * 84;
      float xv[12];
#pragma unroll
      for (int q = 0; q < 3; q++) {
        float4 t = *reinterpret_cast<const float4*>(&sIn[rb + roff[q]]);
        xv[4 * q + 0] = t.x; xv[4 * q + 1] = t.y;
        xv[4 * q + 2] = t.z; xv[4 * q + 3] = t.w;
      }
#pragma unroll
      for (int co = 0; co < 8; co++) {
        const float* wr = w2 + (co * 8 + ci) * 81 + ky * 9;  // wave-uniform
        float w[9];
#pragma unroll
        for (int k = 0; k < 9; k++) w[k] = wr[k];
#pragma unroll
        for (int kx = 0; kx < 9; kx++) {
          acc[co][0] = fmaf(xv[kx], w[kx], acc[co][0]);
          acc[co][1] = fmaf(xv[kx + 2], w[kx], acc[co][1]);
        }
      }
    }
  };

  issue(0); wrlds(); __syncthreads();
#pragma unroll 1
  for (int ci = 0; ci < 8; ci++) {
    if (ci < 7) issue(ci + 1);   // hide HBM latency under compute
    compute(ci);
    __syncthreads();             // reads of sIn done
    if (ci < 7) { wrlds(); __syncthreads(); }
  }

  float* ob = out2 + (size_t)b * (8 * 32 * 32);
  const int oyg = oy0 + oy;
#pragma unroll
  for (int co = 0; co < 8; co++) {
    float2 v = make_float2(RELU(acc[co][0]), RELU(acc[co][1]));
    *reinterpret_cast<float2*>(ob + (co * 32 + oyg) * 32 + 2 * tx) = v;
  }
}

// ---------------- conv3 + mask + pool + head: 8ch 32x32 -> 32ch 16x16 ----------------
// block = ONE image, 256 thr. Wave w owns co-chunk w; lane p: oy=p>>2,
// ox=4*(p&3)+{0..3}. Weights scalar-loaded. Max/pool via shfl_xor.
// LDS rows = 16 quads; slot = seg ^ ((row>>1)&7) -> uniform bank groups for
// both the staged write and the 2oxg-strided b128 read (parity fix).
// Head (pool @ wfc.T -> log_softmax) fused via sPool + wave 0.
__global__ __launch_bounds__(256) void conv3_kernel(
    const float* __restrict__ in, const float* __restrict__ w3,
    const float* __restrict__ wfc, float* __restrict__ masked_out,
    float* __restrict__ pool, float* __restrict__ y) {
  __shared__ float sIn[2 * 39 * 64];
  __shared__ float sPool[32];
  const int tid = threadIdx.x;
  const int b = blockIdx.x;
  const int co0 = __builtin_amdgcn_readfirstlane(tid >> 6) * 8;  // wave-uniform
  const int p = tid & 63;
  const int oy = p >> 2;   // 0..15
  const int oxg = p & 3;   // ox = 4*oxg + {0..3}
  const float* ib = in + (size_t)b * (8 * 32 * 32);

  float acc[8][4];
#pragma unroll
  for (int co = 0; co < 8; co++)
#pragma unroll
    for (int i = 0; i < 4; i++) acc[co][i] = 0.f;

  float4 pre[4];
  // per cg: 2 channels x 39 rows x 10 segs: main segs 0..7 (624), thin 8,9 (156)
  auto issue = [&](int cg) {
#pragma unroll
    for (int k = 0; k < 3; k++) {
      int idx = tid + 256 * k;
      int cr = idx >> 3, seg = idx & 7;
      int c = (cr >= 39) ? 1 : 0;
      int r = cr - 39 * c;
      int gy = r - 4;
      float4 v = make_float4(0.f, 0.f, 0.f, 0.f);
      if (idx < 624 && gy >= 0 && gy < 32 && seg >= 1)
        v = *reinterpret_cast<const float4*>(ib + ((2 * cg + c) * 32 + gy) * 32 + (seg * 4 - 4));
      pre[k] = v;
    }
    {
      int cr = tid >> 1, seg = 8 + (tid & 1);
      int c = (cr >= 39) ? 1 : 0;
      int r = cr - 39 * c;
      int gy = r - 4;
      float4 v = make_float4(0.f, 0.f, 0.f, 0.f);
      if (tid < 156 && gy >= 0 && gy < 32 && seg == 8)
        v = *reinterpret_cast<const float4*>(ib + ((2 * cg + c) * 32 + gy) * 32 + (seg * 4 - 4));
      pre[3] = v;
    }
  };
  auto wrlds = [&]() {
#pragma unroll
    for (int k = 0; k < 3; k++) {
      int idx = tid + 256 * k;
      int cr = idx >> 3, seg = idx & 7;
      if (idx < 624) {
        int slot = seg ^ ((cr >> 1) & 7);
        *reinterpret_cast<float4*>(&sIn[cr * 64 + slot * 4]) = pre[k];
      }
    }
    if (tid < 156) {
      int cr = tid >> 1, seg = 8 + (tid & 1);
      int slot = seg ^ ((cr >> 1) & 7);
      *reinterpret_cast<float4*>(&sIn[cr * 64 + slot * 4]) = pre[3];
    }
  };
  auto compute = [&](int cg) {
#pragma unroll 1
    for (int c = 0; c < 2; c++) {
      const int ci = 2 * cg + c;
#pragma unroll 1
      for (int ky = 0; ky < 9; ky++) {
        const int row = c * 39 + 2 * oy + ky;
        const int rb = row * 64;
        const int key = (row >> 1) & 7;
        float xv[16];
#pragma unroll
        for (int q = 0; q < 4; q++) {
          int slot = (2 * oxg + q) ^ key;
          float4 t = *reinterpret_cast<const float4*>(&sIn[rb + slot * 4]);
          xv[4 * q + 0] = t.x; xv[4 * q + 1] = t.y;
          xv[4 * q + 2] = t.z; xv[4 * q + 3] = t.w;
        }
#pragma unroll
        for (int co = 0; co < 8; co++) {
          const float* wr = w3 + ((co0 + co) * 8 + ci) * 81 + ky * 9;
          float w[9];
#pragma unroll
          for (int k = 0; k < 9; k++) w[k] = wr[k];
#pragma unroll
          for (int kx = 0; kx < 9; kx++)
#pragma unroll
            for (int i = 0; i < 4; i++)
              acc[co][i] = fmaf(xv[kx + 2 * i], w[kx], acc[co][i]);
        }
      }
    }
  };

  issue(0); wrlds(); __syncthreads();
#pragma unroll 1
  for (int cg = 0; cg < 4; cg++) {
    if (cg < 3) issue(cg + 1);
    compute(cg);
    __syncthreads();
    if (cg < 3) { wrlds(); __syncthreads(); }
  }

  // relu + in-wave per-co max (whole 16x16 lives in this wave)
  float thr[8];
#pragma unroll
  for (int co = 0; co < 8; co++) {
#pragma unroll
    for (int i = 0; i < 4; i++) acc[co][i] = RELU(acc[co][i]);
    float m = fmaxf(fmaxf(acc[co][0], acc[co][1]), fmaxf(acc[co][2], acc[co][3]));
#pragma unroll
    for (int k = 32; k >= 1; k >>= 1) m = fmaxf(m, __shfl_xor(m, k));
    thr[co] = m * 0.75f;
  }

  // threshold, masked store (coalesced float4), pool sum
  float* mb = masked_out + ((size_t)b * 32 + co0) * 256 + 4 * p;
  float sum[8];
#pragma unroll
  for (int co = 0; co < 8; co++) {
    float4 v;
    v.x = (acc[co][0] < thr[co]) ? 0.f : acc[co][0];
    v.y = (acc[co][1] < thr[co]) ? 0.f : acc[co][1];
    v.z = (acc[co][2] < thr[co]) ? 0.f : acc[co][2];
    v.w = (acc[co][3] < thr[co]) ? 0.f : acc[co][3];
    *reinterpret_cast<float4*>(mb + co * 256) = v;
    float s = v.x + v.y + v.z + v.w;
#pragma unroll
    for (int k = 32; k >= 1; k >>= 1) s += __shfl_xor(s, k);
    sum[co] = s;
  }
  if (p == 0) {
#pragma unroll
    for (int co = 0; co < 8; co++) {
      float pv = sum[co] * (1.0f / 256.0f);
      pool[(size_t)b * 32 + co0 + co] = pv;
      sPool[co0 + co] = pv;
    }
  }
  __syncthreads();

  // fused head: logits + log_softmax (wave 0, lanes 0..31)
  if (tid < 32) {
    float pv = sPool[tid];
    float l0 = pv * wfc[tid];
    float l1 = pv * wfc[32 + tid];
#pragma unroll
    for (int k = 16; k >= 1; k >>= 1) {
      l0 += __shfl_xor(l0, k);
      l1 += __shfl_xor(l1, k);
    }
    if (tid == 0) {
      float m = fmaxf(l0, l1);
      float lz = logf(expf(l0 - m) + expf(l1 - m)) + m;
      float2 out = make_float2(l0 - lz, l1 - lz);
      *reinterpret_cast<float2*>(y + 2 * b) = out;
    }
  }
}

extern "C" void kernel_launch(void* const* d_in, const int* in_sizes, int n_in,
                              void* d_out, int out_size, void* d_ws, size_t ws_size,
                              hipStream_t stream) {
  const float* x   = (const float*)d_in[0];
  const float* w1  = (const float*)d_in[1];
  const float* w2  = (const float*)d_in[2];
  const float* w3  = (const float*)d_in[3];
  const float* wfc = (const float*)d_in[4];

  float* out = (float*)d_out;
  float* y      = out;                           // [1024, 2]
  float* masked = out + 2048;                    // [1024, 32, 16, 16]
  float* pool   = out + 2048 + 1024 * 32 * 256;  // [1024, 32]

  // workspace: conv1 out (128 MiB) ++ conv2 out (32 MiB)
  float* c1 = (float*)d_ws;
  float* c2 = c1 + (size_t)1024 * 8 * 64 * 64;

  conv1_kernel<<<4096, 256, 0, stream>>>(x, w1, c1);
  conv2_kernel<<<2048, 256, 0, stream>>>(c1, w2, c2);
  conv3_kernel<<<1024, 256, 0, stream>>>(c2, w3, wfc, masked, pool, y);
}